// Round 5
// baseline (180.617 us; speedup 1.0000x reference)
//
#include <hip/hip_runtime.h>
#include <math.h>

#define NB 2
#define NQ 16384        // 32*512 downsampled points per batch
#define IN_H 64
#define IN_W 2048
#define BIG 1e30f
#define NQT (NB * NQ)

typedef __bf16 bf16x8 __attribute__((ext_vector_type(8)));
typedef float f32x16 __attribute__((ext_vector_type(16)));

__device__ inline float med3(float a, float b, float c) {
    return __builtin_amdgcn_fmed3f(a, b, c);
}
// branchless sorted-insert of v into b0<=b1<=b2 (3 VALU)
#define INSERT3(B0, B1, B2, V)                    \
    do { float _v = (V);                          \
         (B2) = med3((B1), (B2), _v);             \
         (B1) = med3((B0), (B1), _v);             \
         (B0) = fminf((B0), _v); } while (0)

union PK { __bf16 h[8]; uint4 u; };

// ---------------------------------------------------------------------------
// pack_kernel: build A-operand (target-side) bf16 fragments for
// mfma_f32_32x32x16_bf16, K-slot layout (t' = -2t, hi/lo bf16 split):
//   k0..7  : [t'xh, t'yh, t'zh, t'xh, t'yh, t'zh, t'xl, t'yl]
//   k8..15 : [t'zl, nth,  ntl,  1,    1,    0,    0,    0  ]
// paired with query-side B slots so that sum_k A*B =
//   -2 s.t (compensated) + ||t||^2 (hi+lo) + ||s||^2 (hi+lo) = d^2.
// Global layout [tile][half][m] x 16B = lane-contiguous for the main kernel.
// Also zeroes accum/done words (replaces the memset dispatch).
// ---------------------------------------------------------------------------
__global__ __launch_bounds__(256) void pack_kernel(
    const float* __restrict__ tgt_pc,   // [B,3,64,2048]
    uint4* __restrict__ packed,
    float* __restrict__ zws)
{
    if (blockIdx.x == 0 && threadIdx.x < 16) zws[threadIdx.x] = 0.f;

    int gid = blockIdx.x * 256 + threadIdx.x;   // [0, NB*NQ)
    int b = gid >> 14, t = gid & (NQ - 1);
    int oh = t >> 9, ow = t & 511;
    const size_t PL = (size_t)IN_H * IN_W;
    size_t base = ((size_t)(b * 3) * IN_H + oh * 2) * IN_W + ow * 4;
    float x = tgt_pc[base], y = tgt_pc[base + PL], z = tgt_pc[base + 2 * PL];
    bool valid = (x != 0.f) || (y != 0.f) || (z != 0.f);
    float nt = valid ? (x * x + y * y + z * z) : BIG;   // sentinel: never wins
    float tx = valid ? -2.f * x : 0.f;
    float ty = valid ? -2.f * y : 0.f;
    float tz = valid ? -2.f * z : 0.f;

    __bf16 txh = (__bf16)tx, tyh = (__bf16)ty, tzh = (__bf16)tz;
    __bf16 txl = (__bf16)(tx - (float)txh);
    __bf16 tyl = (__bf16)(ty - (float)tyh);
    __bf16 tzl = (__bf16)(tz - (float)tzh);
    __bf16 nth = (__bf16)nt;
    __bf16 ntl = (__bf16)(nt - (float)nth);

    PK h0, h1;
    h0.h[0] = txh; h0.h[1] = tyh; h0.h[2] = tzh; h0.h[3] = txh;
    h0.h[4] = tyh; h0.h[5] = tzh; h0.h[6] = txl; h0.h[7] = tyl;
    h1.h[0] = tzl; h1.h[1] = nth; h1.h[2] = ntl; h1.h[3] = (__bf16)1.0f;
    h1.h[4] = (__bf16)1.0f; h1.h[5] = (__bf16)0.0f;
    h1.h[6] = (__bf16)0.0f; h1.h[7] = (__bf16)0.0f;

    int tile = t >> 5, m = t & 31;
    size_t o = (size_t)(b * 512 + tile) * 64 + m;   // uint4 units; tile = 1024 B
    packed[o]      = h0.u;   // half 0 (k0..7)
    packed[o + 32] = h1.u;   // half 1 (k8..15)
}

// ---------------------------------------------------------------------------
// knn_mfma: block = 128 queries (4 waves x 32; lane's query = col = lane&31)
// x one target-quarter (4096 targets = 128 tiles). Double-buffered 16 KB LDS
// chunks (16 tiles); per tile: 1 ds_read_b128 (A frag) + 1 MFMA + 16 INSERT3
// split into even/odd streams. Lane pairs (L, L+32) hold the same query col;
// merged via shfl at the end. grid = NB*4*128 = 1024 blocks (4/CU).
// ---------------------------------------------------------------------------
__global__ __launch_bounds__(256) void knn_mfma(
    const float* __restrict__ src_pc,   // [B,64,2048,3]
    const uint4* __restrict__ packed,
    float* __restrict__ partial)        // [4][3][NQT] plane-major
{
    __shared__ uint4 lds[2][1024];      // 2 x 16 KB chunks
    const int tid = threadIdx.x;
    const int lane = tid & 63;
    const int w = tid >> 6;
    int blk = blockIdx.x;
    int qt = blk & 127;
    int quarter = (blk >> 7) & 3;
    int b = blk >> 9;

    // ---- query-side B fragment (k = (lane>>5)*8 + j, col n = lane&31) ----
    int n = lane & 31;
    int q = qt * 128 + w * 32 + n;
    size_t sbase = (((size_t)b * IN_H + (q >> 9) * 2) * IN_W + (q & 511) * 4) * 3;
    float sx = src_pc[sbase], sy = src_pc[sbase + 1], sz = src_pc[sbase + 2];
    float ns = sx * sx + sy * sy + sz * sz;
    __bf16 sxh = (__bf16)sx, syh = (__bf16)sy, szh = (__bf16)sz;
    __bf16 sxl = (__bf16)(sx - (float)sxh);
    __bf16 syl = (__bf16)(sy - (float)syh);
    __bf16 szl = (__bf16)(sz - (float)szh);
    __bf16 nsh = (__bf16)ns;
    __bf16 nsl = (__bf16)(ns - (float)nsh);
    bf16x8 bq;
    if ((lane >> 5) == 0) {
        bq[0] = sxh; bq[1] = syh; bq[2] = szh; bq[3] = sxl;
        bq[4] = syl; bq[5] = szl; bq[6] = sxh; bq[7] = syh;
    } else {
        bq[0] = szh; bq[1] = (__bf16)1.0f; bq[2] = (__bf16)1.0f; bq[3] = nsh;
        bq[4] = nsl; bq[5] = (__bf16)0.0f; bq[6] = (__bf16)0.0f; bq[7] = (__bf16)0.0f;
    }

    f32x16 zero;
    #pragma unroll
    for (int i = 0; i < 16; ++i) zero[i] = 0.f;

    float e0 = BIG, e1 = BIG, e2 = BIG, o0 = BIG, o1 = BIG, o2 = BIG;

    // this quarter's 128 tiles, 64 uint4 each
    const uint4* pkq = packed + (size_t)b * 32768 + (size_t)quarter * 8192;

    uint4 r[4];
    #pragma unroll
    for (int i = 0; i < 4; ++i) r[i] = pkq[tid + 256 * i];          // chunk 0
    #pragma unroll
    for (int i = 0; i < 4; ++i) lds[0][tid + 256 * i] = r[i];
    __syncthreads();

    for (int c = 0; c < 8; ++c) {
        int cur = c & 1;
        uint4 rn[4];
        if (c < 7) {
            const uint4* s = pkq + (c + 1) * 1024;
            #pragma unroll
            for (int i = 0; i < 4; ++i) rn[i] = s[tid + 256 * i];
        }
        const uint4* buf = lds[cur];
        #pragma unroll
        for (int t = 0; t < 16; ++t) {
            bf16x8 af = __builtin_bit_cast(bf16x8, buf[t * 64 + lane]);
            f32x16 d = __builtin_amdgcn_mfma_f32_32x32x16_bf16(af, bq, zero, 0, 0, 0);
            #pragma unroll
            for (int i = 0; i < 16; i += 2) {
                INSERT3(e0, e1, e2, d[i]);
                INSERT3(o0, o1, o2, d[i + 1]);
            }
        }
        if (c < 7) {
            #pragma unroll
            for (int i = 0; i < 4; ++i) lds[1 - cur][tid + 256 * i] = rn[i];
        }
        __syncthreads();
    }

    // ---- epilogue: merge odd stream, then lane L <- L+32 (same query) ----
    INSERT3(e0, e1, e2, o0);
    INSERT3(e0, e1, e2, o1);
    INSERT3(e0, e1, e2, o2);
    float f0 = __shfl_down(e0, 32, 64);
    float f1 = __shfl_down(e1, 32, 64);
    float f2 = __shfl_down(e2, 32, 64);
    if (lane < 32) {
        INSERT3(e0, e1, e2, f0);
        INSERT3(e0, e1, e2, f1);
        INSERT3(e0, e1, e2, f2);
        int gq = b * NQ + q;
        partial[(quarter * 3 + 0) * NQT + gq] = e0;
        partial[(quarter * 3 + 1) * NQT + gq] = e1;
        partial[(quarter * 3 + 2) * NQT + gq] = e2;
    }
}

// ---------------------------------------------------------------------------
// merge_final: per query merge 4 quarter-trios, sqrt+clamp, masked reduce,
// per-batch atomics; last finished block computes the scalar output.
// ---------------------------------------------------------------------------
__global__ __launch_bounds__(256) void merge_final(
    const float* __restrict__ partial,
    const float* __restrict__ src_pc,
    float* __restrict__ accum,          // {sum0,cnt0,sum1,cnt1}
    int* __restrict__ done_cnt,
    float* __restrict__ out)
{
    int gid = blockIdx.x * 256 + threadIdx.x;   // < NQT
    int b = gid >> 14;
    int q = gid & (NQ - 1);

    float b0 = BIG, b1 = BIG, b2 = BIG;
    #pragma unroll
    for (int c = 0; c < 12; ++c) {
        float v = partial[c * NQT + gid];       // coalesced plane reads
        INSERT3(b0, b1, b2, v);
    }

    size_t base = (((size_t)b * IN_H + (q >> 9) * 2) * IN_W + (q & 511) * 4) * 3;
    float x = src_pc[base], y = src_pc[base + 1], z = src_pc[base + 2];
    float wt = ((x != 0.f) || (y != 0.f) || (z != 0.f)) ? 1.f : 0.f;

    float d = fminf(sqrtf(fmaxf(b0, 0.f)), 1e10f)
            + fminf(sqrtf(fmaxf(b1, 0.f)), 1e10f)
            + fminf(sqrtf(fmaxf(b2, 0.f)), 1e10f);
    float dsum = d * wt;

    #pragma unroll
    for (int off = 32; off > 0; off >>= 1) {
        dsum += __shfl_down(dsum, off, 64);
        wt   += __shfl_down(wt, off, 64);
    }
    __shared__ float sd[4], sw4[4];
    int lane = threadIdx.x & 63, wv = threadIdx.x >> 6;
    if (lane == 0) { sd[wv] = dsum; sw4[wv] = wt; }
    __syncthreads();
    if (threadIdx.x == 0) {
        atomicAdd(&accum[b * 2 + 0], sd[0] + sd[1] + sd[2] + sd[3]);
        atomicAdd(&accum[b * 2 + 1], sw4[0] + sw4[1] + sw4[2] + sw4[3]);
        __threadfence();
        int done = atomicAdd(done_cnt, 1);
        if (done == (int)gridDim.x - 1) {
            float s0 = atomicAdd(&accum[0], 0.f);
            float c0 = atomicAdd(&accum[1], 0.f);
            float s1 = atomicAdd(&accum[2], 0.f);
            float c1 = atomicAdd(&accum[3], 0.f);
            float r = s0 / (3.0f * fmaxf(c0, 1.0f))
                    + s1 / (3.0f * fmaxf(c1, 1.0f));
            out[0] = r / (float)NB;
        }
    }
}

// ---------------------------------------------------------------------------
extern "C" void kernel_launch(void* const* d_in, const int* in_sizes, int n_in,
                              void* d_out, int out_size, void* d_ws, size_t ws_size,
                              hipStream_t stream) {
    const float* src_pc = (const float*)d_in[0];   // [2,64,2048,3]
    const float* tgt_pc = (const float*)d_in[1];   // [2,3,64,2048]
    float* out = (float*)d_out;

    char* ws = (char*)d_ws;
    float* accum   = (float*)ws;                    // 4 floats @ 0
    int*   done    = (int*)(ws + 32);               // 1 int    @ 32
    float* partial = (float*)(ws + 64);             // 12 * 32768 floats = 1.5 MB
    uint4* packed  = (uint4*)(ws + 2097152);        // 1 MB packed A fragments

    pack_kernel<<<NQT / 256, 256, 0, stream>>>(tgt_pc, packed, (float*)ws);
    knn_mfma<<<NB * 4 * 128, 256, 0, stream>>>(src_pc, packed, partial);
    merge_final<<<NQT / 256, 256, 0, stream>>>(partial, src_pc, accum, done, out);
}

// Round 6
// 119.960 us; speedup vs baseline: 1.5056x; 1.5056x over previous
//
#include <hip/hip_runtime.h>
#include <math.h>

#define NB 2
#define NQ 16384        // 32*512 downsampled points per batch
#define IN_H 64
#define IN_W 2048
#define BIG 1e30f
#define NQT (NB * NQ)

typedef __bf16 bf16x8 __attribute__((ext_vector_type(8)));
typedef float f32x16 __attribute__((ext_vector_type(16)));

__device__ inline float med3(float a, float b, float c) {
    return __builtin_amdgcn_fmed3f(a, b, c);
}
// branchless sorted-insert of v into b0<=b1<=b2 (3 VALU)
#define INSERT3(B0, B1, B2, V)                    \
    do { float _v = (V);                          \
         (B2) = med3((B1), (B2), _v);             \
         (B1) = med3((B0), (B1), _v);             \
         (B0) = fminf((B0), _v); } while (0)

union PK { __bf16 h[8]; uint4 u; };

// ---------------------------------------------------------------------------
// pack_kernel: (a) bf16 compensated A-fragments for mfma_f32_32x32x16_bf16
// (layout verified in R5, absmax was 0.0), (b) compact fp32 float4
// (x,y,z,||t||^2) per target for the exact pass-2 recompute (invalid ->
// xyz=0, w=1e20 so sqrt=1e10, matching the reference's INVALID_DIST).
// Also zeroes the accum/done words.
// ---------------------------------------------------------------------------
__global__ __launch_bounds__(256) void pack_kernel(
    const float* __restrict__ tgt_pc,   // [B,3,64,2048]
    uint4* __restrict__ packed,
    float4* __restrict__ tgt4,
    float* __restrict__ zws)
{
    if (blockIdx.x == 0 && threadIdx.x < 16) zws[threadIdx.x] = 0.f;

    int gid = blockIdx.x * 256 + threadIdx.x;   // [0, NB*NQ)
    int b = gid >> 14, t = gid & (NQ - 1);
    int oh = t >> 9, ow = t & 511;
    const size_t PL = (size_t)IN_H * IN_W;
    size_t base = ((size_t)(b * 3) * IN_H + oh * 2) * IN_W + ow * 4;
    float x = tgt_pc[base], y = tgt_pc[base + PL], z = tgt_pc[base + 2 * PL];
    bool valid = (x != 0.f) || (y != 0.f) || (z != 0.f);
    float ntx = x * x + y * y + z * z;
    float nt = valid ? ntx : BIG;               // pass-1 sentinel
    float tx = valid ? -2.f * x : 0.f;
    float ty = valid ? -2.f * y : 0.f;
    float tz = valid ? -2.f * z : 0.f;

    __bf16 txh = (__bf16)tx, tyh = (__bf16)ty, tzh = (__bf16)tz;
    __bf16 txl = (__bf16)(tx - (float)txh);
    __bf16 tyl = (__bf16)(ty - (float)tyh);
    __bf16 tzl = (__bf16)(tz - (float)tzh);
    __bf16 nth = (__bf16)nt;
    __bf16 ntl = (__bf16)(nt - (float)nth);

    PK h0, h1;
    h0.h[0] = txh; h0.h[1] = tyh; h0.h[2] = tzh; h0.h[3] = txh;
    h0.h[4] = tyh; h0.h[5] = tzh; h0.h[6] = txl; h0.h[7] = tyl;
    h1.h[0] = tzl; h1.h[1] = nth; h1.h[2] = ntl; h1.h[3] = (__bf16)1.0f;
    h1.h[4] = (__bf16)1.0f; h1.h[5] = (__bf16)0.0f;
    h1.h[6] = (__bf16)0.0f; h1.h[7] = (__bf16)0.0f;

    int tile = t >> 5, m = t & 31;
    size_t o = (size_t)(b * 512 + tile) * 64 + m;   // uint4 units
    packed[o]      = h0.u;   // k0..7
    packed[o + 32] = h1.u;   // k8..15

    // exact-recompute buffer: raw xyz (zeroed if invalid), w = nt or 1e20
    tgt4[gid] = make_float4(valid ? x : 0.f, valid ? y : 0.f,
                            valid ? z : 0.f, valid ? ntx : 1e20f);
}

// ---------------------------------------------------------------------------
// knn_mfma: block = 128 queries (4 waves x 32, query col = lane&31) x one
// target-quarter (4096 targets = 128 tiles), double-buffered 16 KB chunks.
// Pass 1 (approx, bf16-compensated MFMA): per tile 1 ds_read_b128 + 1 MFMA +
// min-tree(16) + pack tile idx into low 7 mantissa bits + INSERT3 -> top-3
// candidate tiles per lane. Guarantee: a lane's top-3 values lie in its 3
// smallest-min tiles. Pass 2 (exact fp32): recompute 3x16 candidate values
// from tgt4, exact top-3, merge lane halves via shfl.
// ---------------------------------------------------------------------------
__global__ __launch_bounds__(256, 4) void knn_mfma(
    const float* __restrict__ src_pc,   // [B,64,2048,3]
    const uint4* __restrict__ packed,
    const float4* __restrict__ tgt4,
    float* __restrict__ partial)        // [4][3][NQT] plane-major
{
    __shared__ uint4 lds[2][1024];      // 2 x 16 KB chunks (16 tiles each)
    const int tid = threadIdx.x;
    const int lane = tid & 63;
    const int w = tid >> 6;
    int blk = blockIdx.x;
    int qt = blk & 127;
    int quarter = (blk >> 7) & 3;
    int b = blk >> 9;

    // ---- query-side B fragment (k = (lane>>5)*8 + j, col n = lane&31) ----
    int n = lane & 31;
    int q = qt * 128 + w * 32 + n;
    size_t sbase = (((size_t)b * IN_H + (q >> 9) * 2) * IN_W + (q & 511) * 4) * 3;
    float sx = src_pc[sbase], sy = src_pc[sbase + 1], sz = src_pc[sbase + 2];
    float ns = sx * sx + sy * sy + sz * sz;
    __bf16 sxh = (__bf16)sx, syh = (__bf16)sy, szh = (__bf16)sz;
    __bf16 sxl = (__bf16)(sx - (float)sxh);
    __bf16 syl = (__bf16)(sy - (float)syh);
    __bf16 szl = (__bf16)(sz - (float)szh);
    __bf16 nsh = (__bf16)ns;
    __bf16 nsl = (__bf16)(ns - (float)nsh);
    bf16x8 bq;
    if ((lane >> 5) == 0) {
        bq[0] = sxh; bq[1] = syh; bq[2] = szh; bq[3] = sxl;
        bq[4] = syl; bq[5] = szl; bq[6] = sxh; bq[7] = syh;
    } else {
        bq[0] = szh; bq[1] = (__bf16)1.0f; bq[2] = (__bf16)1.0f; bq[3] = nsh;
        bq[4] = nsl; bq[5] = (__bf16)0.0f; bq[6] = (__bf16)0.0f; bq[7] = (__bf16)0.0f;
    }

    f32x16 zero;
    #pragma unroll
    for (int i = 0; i < 16; ++i) zero[i] = 0.f;

    float c0 = BIG, c1 = BIG, c2 = BIG;    // packed (min | tile-idx) top-3

    const uint4* pkq = packed + (size_t)b * 32768 + (size_t)quarter * 8192;

    uint4 r[4];
    #pragma unroll
    for (int i = 0; i < 4; ++i) r[i] = pkq[tid + 256 * i];          // chunk 0
    #pragma unroll
    for (int i = 0; i < 4; ++i) lds[0][tid + 256 * i] = r[i];
    __syncthreads();

    for (int c = 0; c < 8; ++c) {
        int cur = c & 1;
        uint4 rn[4];
        if (c < 7) {
            const uint4* s = pkq + (c + 1) * 1024;
            #pragma unroll
            for (int i = 0; i < 4; ++i) rn[i] = s[tid + 256 * i];
        }
        const uint4* buf = lds[cur];
        #pragma unroll 2
        for (int t = 0; t < 16; ++t) {
            bf16x8 af = __builtin_bit_cast(bf16x8, buf[t * 64 + lane]);
            f32x16 d = __builtin_amdgcn_mfma_f32_32x32x16_bf16(af, bq, zero, 0, 0, 0);
            // min of 16 (fminf nest -> fused v_min3 tree, ~8 ops)
            float m0 = fminf(fminf(d[0], d[1]), fminf(d[2], d[3]));
            float m1 = fminf(fminf(d[4], d[5]), fminf(d[6], d[7]));
            float m2 = fminf(fminf(d[8], d[9]), fminf(d[10], d[11]));
            float m3 = fminf(fminf(d[12], d[13]), fminf(d[14], d[15]));
            float m = fminf(fminf(m0, m1), fminf(m2, m3));
            // pack tile index (0..127) into low 7 mantissa bits
            unsigned u = (__float_as_uint(m) & ~127u) | (unsigned)(c * 16 + t);
            float pv = __uint_as_float(u);
            INSERT3(c0, c1, c2, pv);
        }
        if (c < 7) {
            #pragma unroll
            for (int i = 0; i < 4; ++i) lds[1 - cur][tid + 256 * i] = rn[i];
        }
        __syncthreads();
    }

    // ---- pass 2: exact fp32 recompute of the 3 candidate tiles ----
    int half = lane >> 5;
    int ti[3] = { (int)(__float_as_uint(c0) & 127u),
                  (int)(__float_as_uint(c1) & 127u),
                  (int)(__float_as_uint(c2) & 127u) };
    float e0 = BIG, e1 = BIG, e2 = BIG;
    const float4* t4b = tgt4 + (size_t)b * NQ + (size_t)quarter * 4096;
    #pragma unroll
    for (int i = 0; i < 3; ++i) {
        int tbase = ti[i] * 32 + 4 * half;
        #pragma unroll
        for (int rr = 0; rr < 16; ++rr) {
            int row = (rr & 3) + 8 * (rr >> 2);     // + 4*half folded in tbase
            float4 t4 = t4b[tbase + row];
            float dot = sx * t4.x;
            dot = fmaf(sy, t4.y, dot);
            dot = fmaf(sz, t4.z, dot);
            float d2 = fmaf(-2.f, dot, ns + t4.w);  // exact-form d^2
            INSERT3(e0, e1, e2, d2);
        }
    }

    // ---- merge lane halves (L <- L+32, same query col), write planes ----
    float f0 = __shfl_down(e0, 32, 64);
    float f1 = __shfl_down(e1, 32, 64);
    float f2 = __shfl_down(e2, 32, 64);
    if (lane < 32) {
        INSERT3(e0, e1, e2, f0);
        INSERT3(e0, e1, e2, f1);
        INSERT3(e0, e1, e2, f2);
        int gq = b * NQ + q;
        partial[(quarter * 3 + 0) * NQT + gq] = e0;
        partial[(quarter * 3 + 1) * NQT + gq] = e1;
        partial[(quarter * 3 + 2) * NQT + gq] = e2;
    }
}

// ---------------------------------------------------------------------------
// merge_final: per query merge 4 quarter-trios, sqrt+clamp, masked reduce,
// per-batch atomics; last finished block computes the scalar output.
// ---------------------------------------------------------------------------
__global__ __launch_bounds__(256) void merge_final(
    const float* __restrict__ partial,
    const float* __restrict__ src_pc,
    float* __restrict__ accum,          // {sum0,cnt0,sum1,cnt1}
    int* __restrict__ done_cnt,
    float* __restrict__ out)
{
    int gid = blockIdx.x * 256 + threadIdx.x;   // < NQT
    int b = gid >> 14;
    int q = gid & (NQ - 1);

    float b0 = BIG, b1 = BIG, b2 = BIG;
    #pragma unroll
    for (int c = 0; c < 12; ++c) {
        float v = partial[c * NQT + gid];       // coalesced plane reads
        INSERT3(b0, b1, b2, v);
    }

    size_t base = (((size_t)b * IN_H + (q >> 9) * 2) * IN_W + (q & 511) * 4) * 3;
    float x = src_pc[base], y = src_pc[base + 1], z = src_pc[base + 2];
    float wt = ((x != 0.f) || (y != 0.f) || (z != 0.f)) ? 1.f : 0.f;

    float d = fminf(sqrtf(fmaxf(b0, 0.f)), 1e10f)
            + fminf(sqrtf(fmaxf(b1, 0.f)), 1e10f)
            + fminf(sqrtf(fmaxf(b2, 0.f)), 1e10f);
    float dsum = d * wt;

    #pragma unroll
    for (int off = 32; off > 0; off >>= 1) {
        dsum += __shfl_down(dsum, off, 64);
        wt   += __shfl_down(wt, off, 64);
    }
    __shared__ float sd[4], sw4[4];
    int lane = threadIdx.x & 63, wv = threadIdx.x >> 6;
    if (lane == 0) { sd[wv] = dsum; sw4[wv] = wt; }
    __syncthreads();
    if (threadIdx.x == 0) {
        atomicAdd(&accum[b * 2 + 0], sd[0] + sd[1] + sd[2] + sd[3]);
        atomicAdd(&accum[b * 2 + 1], sw4[0] + sw4[1] + sw4[2] + sw4[3]);
        __threadfence();
        int done = atomicAdd(done_cnt, 1);
        if (done == (int)gridDim.x - 1) {
            float s0 = atomicAdd(&accum[0], 0.f);
            float c0 = atomicAdd(&accum[1], 0.f);
            float s1 = atomicAdd(&accum[2], 0.f);
            float c1 = atomicAdd(&accum[3], 0.f);
            float r = s0 / (3.0f * fmaxf(c0, 1.0f))
                    + s1 / (3.0f * fmaxf(c1, 1.0f));
            out[0] = r / (float)NB;
        }
    }
}

// ---------------------------------------------------------------------------
extern "C" void kernel_launch(void* const* d_in, const int* in_sizes, int n_in,
                              void* d_out, int out_size, void* d_ws, size_t ws_size,
                              hipStream_t stream) {
    const float* src_pc = (const float*)d_in[0];   // [2,64,2048,3]
    const float* tgt_pc = (const float*)d_in[1];   // [2,3,64,2048]
    float* out = (float*)d_out;

    char* ws = (char*)d_ws;
    float*  accum   = (float*)ws;                   // 4 floats @ 0
    int*    done    = (int*)(ws + 32);              // 1 int    @ 32
    float*  partial = (float*)(ws + 64);            // 1.5 MB
    uint4*  packed  = (uint4*)(ws + 2097152);       // 1 MB
    float4* tgt4    = (float4*)(ws + 3145728);      // 512 KB

    pack_kernel<<<NQT / 256, 256, 0, stream>>>(tgt_pc, packed, tgt4, (float*)ws);
    knn_mfma<<<NB * 4 * 128, 256, 0, stream>>>(src_pc, packed, tgt4, partial);
    merge_final<<<NQT / 256, 256, 0, stream>>>(partial, src_pc, accum, done, out);
}